// Round 3
// baseline (273.912 us; speedup 1.0000x reference)
//
#include <hip/hip_runtime.h>
#include <hip/hip_bf16.h>
#include <stdint.h>

#define N_DIM 8192
#define D_DIM 512
#define BM 128
#define BN 128
#define BK 64
#define RSTR 132   // recs row stride in floats: 16B-aligned rows, +4-bank rotation

typedef __attribute__((ext_vector_type(8))) short bf16x8;
typedef __attribute__((ext_vector_type(4))) float f32x4;

__device__ __forceinline__ unsigned short f2bf(float f) {
    unsigned int x = __float_as_uint(f);
    x += 0x7fffu + ((x >> 16) & 1u);
    return (unsigned short)(x >> 16);
}

// ---------------- prep: f32 -> bf16, plus row squared norms ----------------
__global__ void __launch_bounds__(256) prep_kernel(
    const float* __restrict__ U, const float* __restrict__ V,
    unsigned short* __restrict__ Ub, unsigned short* __restrict__ Vb,
    float* __restrict__ usq, float* __restrict__ vsq)
{
    int row = blockIdx.x;
    const float* src;
    unsigned short* dst;
    float* sq;
    if (row < N_DIM) {
        src = U + (size_t)row * D_DIM;
        dst = Ub + (size_t)row * D_DIM;
        sq  = usq + row;
    } else {
        int r = row - N_DIM;
        src = V + (size_t)r * D_DIM;
        dst = Vb + (size_t)r * D_DIM;
        sq  = vsq + r;
    }
    int t = threadIdx.x;
    float2 v = *reinterpret_cast<const float2*>(src + 2 * t);
    float s = v.x * v.x + v.y * v.y;
    ushort2 b;
    b.x = f2bf(v.x);
    b.y = f2bf(v.y);
    *reinterpret_cast<ushort2*>(dst + 2 * t) = b;

    #pragma unroll
    for (int o = 32; o > 0; o >>= 1) s += __shfl_down(s, o, 64);
    __shared__ float red[4];
    if ((t & 63) == 0) red[t >> 6] = s;
    __syncthreads();
    if (t == 0) *sq = red[0] + red[1] + red[2] + red[3];
}

// ---------------- fused GEMM + loss-reduction, tile-pair persistent ----------------
// Each block owns two adjacent 128x128 tiles (same tile_m row).
// tile0 K-loop plain; tile0 epilogue interleaved into tile1's K-loop
// (M/W float4 loads issued post-staging-barrier, consumed post-MFMA);
// tile1 epilogue exposed. recs is a separate 64x132 f32 LDS buffer.
__global__ void __launch_bounds__(256, 2) fused_kernel(
    const unsigned short* __restrict__ Ub, const unsigned short* __restrict__ Vb,
    const float* __restrict__ Mg, const float* __restrict__ Wg,
    const float* __restrict__ usq, const float* __restrict__ vsq,
    double* __restrict__ acc)
{
    __shared__ alignas(16) char smem[BM * BK * 2 + BN * BK * 2];  // 32 KiB staging
    __shared__ alignas(16) float recs[64 * RSTR];                 // 33 KiB
    __shared__ float red1[4], red2[4];
    char* As = smem;
    char* Bs = smem + BM * BK * 2;

    const int t    = threadIdx.x;
    const int lane = t & 63;
    const int wave = t >> 6;
    const int wm   = wave >> 1;
    const int wn   = wave & 1;

    const int bid    = blockIdx.x;        // 0..2047, row-major over tile pairs
    const int tile_m = bid >> 5;
    const int pair   = bid & 31;
    const int row0   = tile_m * BM;
    const int col0_0 = (pair * 2) * BN;
    const int col0_1 = (pair * 2 + 1) * BN;

    const int rloc = t >> 5;              // 0..7
    const int c4   = (t & 31) * 4;        // 0..124

    float s1 = 0.f, s2 = 0.f;

    auto As3 = (__attribute__((address_space(3))) char*)As;
    auto Bs3 = (__attribute__((address_space(3))) char*)Bs;

    auto stage = [&](const unsigned short* Ua, const unsigned short* Va, int k0) {
        #pragma unroll
        for (int c = 0; c < 4; ++c) {
            int s   = c * 256 + t;
            int row = s >> 3;
            int kg  = s & 7;
            int kgs = kg ^ (row & 7);    // inverse-swizzled global source
            __builtin_amdgcn_global_load_lds(
                (const __attribute__((address_space(1))) void*)(Ua + (size_t)row * D_DIM + k0 + kgs * 8),
                (__attribute__((address_space(3))) void*)(As3 + s * 16), 16, 0, 0);
            __builtin_amdgcn_global_load_lds(
                (const __attribute__((address_space(1))) void*)(Va + (size_t)row * D_DIM + k0 + kgs * 8),
                (__attribute__((address_space(3))) void*)(Bs3 + s * 16), 16, 0, 0);
        }
    };

    auto mma = [&](f32x4 (&a)[4][4]) {
        #pragma unroll
        for (int kc = 0; kc < 2; ++kc) {
            bf16x8 af[4], bfr[4];
            const int kgw = kc * 4 + (lane >> 4);
            #pragma unroll
            for (int i = 0; i < 4; ++i) {
                int ra = wm * 64 + i * 16 + (lane & 15);
                af[i]  = *reinterpret_cast<const bf16x8*>(As + ra * (BK * 2) + ((kgw ^ (ra & 7)) * 16));
                int rb = wn * 64 + i * 16 + (lane & 15);
                bfr[i] = *reinterpret_cast<const bf16x8*>(Bs + rb * (BK * 2) + ((kgw ^ (rb & 7)) * 16));
            }
            #pragma unroll
            for (int i = 0; i < 4; ++i)
                #pragma unroll
                for (int j = 0; j < 4; ++j)
                    a[i][j] = __builtin_amdgcn_mfma_f32_16x16x32_bf16(af[i], bfr[j], a[i][j], 0, 0, 0);
        }
    };

    // C/D layout (16x16x32): col = lane&15, row = (lane>>4)*4 + reg
    auto dump_half = [&](f32x4 (&a)[4][4], int h) {
        if (wm == h) {
            #pragma unroll
            for (int i = 0; i < 4; ++i)
                #pragma unroll
                for (int j = 0; j < 4; ++j)
                    #pragma unroll
                    for (int q = 0; q < 4; ++q)
                        recs[(i * 16 + (lane >> 4) * 4 + q) * RSTR +
                             wn * 64 + j * 16 + (lane & 15)] = a[i][j][q];
        }
    };

    const f32x4 zero = {0.f, 0.f, 0.f, 0.f};
    const unsigned short* Ua = Ub + (size_t)row0 * D_DIM;

    // ---- tile0 K-loop (plain) ----
    f32x4 a0[4][4];
    #pragma unroll
    for (int i = 0; i < 4; ++i)
        #pragma unroll
        for (int j = 0; j < 4; ++j) a0[i][j] = zero;
    {
        const unsigned short* Va = Vb + (size_t)col0_0 * D_DIM;
        for (int kt = 0; kt < D_DIM / BK; ++kt) {
            stage(Ua, Va, kt * BK);
            __syncthreads();
            mma(a0);
            __syncthreads();
        }
    }
    dump_half(a0, 0);   // recs <- rows 0..63 of tile0 (ordered by next barrier)

    // ---- tile1 K-loop with tile0 epilogue interleaved ----
    f32x4 a1[4][4];
    #pragma unroll
    for (int i = 0; i < 4; ++i)
        #pragma unroll
        for (int j = 0; j < 4; ++j) a1[i][j] = zero;

    const f32x4 vs0 = *reinterpret_cast<const f32x4*>(vsq + col0_0 + c4);
    {
        const unsigned short* Va = Vb + (size_t)col0_1 * D_DIM;
        #pragma unroll
        for (int kt = 0; kt < D_DIM / BK; ++kt) {
            stage(Ua, Va, kt * BK);
            if (kt == 4) dump_half(a0, 1);   // half0 reads done at kt=3's barrier
            __syncthreads();

            // issue M/W loads for 2 cells of tile0 (land under ds_read+MFMA)
            const int h   = kt >> 2;
            const int sp  = kt & 3;
            const int r0c = rloc + (2 * sp) * 8;   // 0..63 local row in half
            const int r1c = r0c + 8;
            const float* Mp = Mg + (size_t)(row0 + h * 64) * N_DIM + col0_0 + c4;
            const float* Wp = Wg + (size_t)(row0 + h * 64) * N_DIM + col0_0 + c4;
            f32x4 mv0 = *reinterpret_cast<const f32x4*>(Mp + (size_t)r0c * N_DIM);
            f32x4 mv1 = *reinterpret_cast<const f32x4*>(Mp + (size_t)r1c * N_DIM);
            f32x4 wv0 = *reinterpret_cast<const f32x4*>(Wp + (size_t)r0c * N_DIM);
            f32x4 wv1 = *reinterpret_cast<const f32x4*>(Wp + (size_t)r1c * N_DIM);
            float us0 = usq[row0 + h * 64 + r0c];
            float us1 = usq[row0 + h * 64 + r1c];

            mma(a1);

            f32x4 rc0 = *reinterpret_cast<const f32x4*>(recs + r0c * RSTR + c4);
            f32x4 rc1 = *reinterpret_cast<const f32x4*>(recs + r1c * RSTR + c4);
            #pragma unroll
            for (int c = 0; c < 4; ++c) {
                float d0 = rc0[c] - mv0[c];
                s1 = fmaf(d0, d0, s1);
                s2 = fmaf(wv0[c], us0 + vs0[c] - 2.f * rc0[c], s2);
                float d1 = rc1[c] - mv1[c];
                s1 = fmaf(d1, d1, s1);
                s2 = fmaf(wv1[c], us1 + vs0[c] - 2.f * rc1[c], s2);
            }
            __syncthreads();
        }
    }

    // ---- tile1 epilogue (exposed, two halves through recs) ----
    const f32x4 vs1 = *reinterpret_cast<const f32x4*>(vsq + col0_1 + c4);
    #pragma unroll
    for (int hh = 0; hh < 2; ++hh) {
        dump_half(a1, hh);   // prior recs reads ordered by preceding barrier
        __syncthreads();

        const float* Mp = Mg + (size_t)(row0 + hh * 64) * N_DIM + col0_1 + c4;
        const float* Wp = Wg + (size_t)(row0 + hh * 64) * N_DIM + col0_1 + c4;

        #pragma unroll
        for (int kk = 0; kk < 2; ++kk) {
            f32x4 mv[4], wv[4];
            float usr[4];
            #pragma unroll
            for (int b = 0; b < 4; ++b) {
                int r  = rloc + (kk * 4 + b) * 8;
                mv[b]  = *reinterpret_cast<const f32x4*>(Mp + (size_t)r * N_DIM);
                wv[b]  = *reinterpret_cast<const f32x4*>(Wp + (size_t)r * N_DIM);
                usr[b] = usq[row0 + hh * 64 + r];
            }
            #pragma unroll
            for (int b = 0; b < 4; ++b) {
                int r = rloc + (kk * 4 + b) * 8;
                f32x4 rc = *reinterpret_cast<const f32x4*>(recs + r * RSTR + c4);
                #pragma unroll
                for (int c = 0; c < 4; ++c) {
                    float d = rc[c] - mv[b][c];
                    s1 = fmaf(d, d, s1);
                    s2 = fmaf(wv[b][c], usr[b] + vs1[c] - 2.f * rc[c], s2);
                }
            }
        }
        __syncthreads();   // before next half overwrites recs
    }

    // ---- block reduction + atomics ----
    #pragma unroll
    for (int o = 32; o > 0; o >>= 1) {
        s1 += __shfl_down(s1, o, 64);
        s2 += __shfl_down(s2, o, 64);
    }
    if (lane == 0) { red1[wave] = s1; red2[wave] = s2; }
    __syncthreads();
    if (t == 0) {
        double a1s = (double)red1[0] + red1[1] + red1[2] + red1[3];
        double a2s = (double)red2[0] + red2[1] + red2[2] + red2[3];
        atomicAdd(acc, a1s);
        atomicAdd(acc + 1, a2s);
    }
}

// ---------------- finalize ----------------
__global__ void finalize_kernel(const double* __restrict__ acc,
                                const float* __restrict__ alpha,
                                float* __restrict__ out)
{
    double tot = acc[0] + (double)alpha[0] * acc[1];
    out[0] = (float)(tot / ((double)N_DIM * (double)N_DIM));
}

extern "C" void kernel_launch(void* const* d_in, const int* in_sizes, int n_in,
                              void* d_out, int out_size, void* d_ws, size_t ws_size,
                              hipStream_t stream) {
    const float* U     = (const float*)d_in[0];
    const float* V     = (const float*)d_in[1];
    const float* Mg    = (const float*)d_in[2];
    const float* Wg    = (const float*)d_in[3];
    const float* alpha = (const float*)d_in[4];

    char* ws = (char*)d_ws;
    unsigned short* Ub = (unsigned short*)ws;                          // 8 MiB
    unsigned short* Vb = (unsigned short*)(ws + 8u * 1024 * 1024);     // 8 MiB
    float* usq = (float*)(ws + 16u * 1024 * 1024);                     // 32 KiB
    float* vsq = (float*)(ws + 16u * 1024 * 1024 + 32u * 1024);       // 32 KiB
    double* acc = (double*)(ws + 16u * 1024 * 1024 + 64u * 1024);     // 16 B

    hipMemsetAsync(acc, 0, 2 * sizeof(double), stream);
    prep_kernel<<<2 * N_DIM, 256, 0, stream>>>(U, V, Ub, Vb, usq, vsq);
    fused_kernel<<<(N_DIM / BM) * (N_DIM / BN) / 2, 256, 0, stream>>>(
        Ub, Vb, Mg, Wg, usq, vsq, acc);
    finalize_kernel<<<1, 1, 0, stream>>>(acc, alpha, (float*)d_out);
}

// Round 4
// 218.658 us; speedup vs baseline: 1.2527x; 1.2527x over previous
//
#include <hip/hip_runtime.h>
#include <hip/hip_bf16.h>
#include <stdint.h>

#define N_DIM 8192
#define D_DIM 512
#define BM 128
#define BN 128
#define BK 64
#define RSTR 136            // recs row stride in bf16 elems (272 B -> 4-bank rotation/row)
#define TPB 4               // tiles per block (same tile_m row)

typedef __attribute__((ext_vector_type(8))) short bf16x8;
typedef __attribute__((ext_vector_type(4))) float f32x4;

__device__ __forceinline__ unsigned short f2bf(float f) {
    unsigned int x = __float_as_uint(f);
    x += 0x7fffu + ((x >> 16) & 1u);
    return (unsigned short)(x >> 16);
}
__device__ __forceinline__ float bf2f(unsigned short u) {
    return __uint_as_float(((unsigned int)u) << 16);
}

// ---------------- prep: f32 -> bf16, plus row squared norms ----------------
__global__ void __launch_bounds__(256) prep_kernel(
    const float* __restrict__ U, const float* __restrict__ V,
    unsigned short* __restrict__ Ub, unsigned short* __restrict__ Vb,
    float* __restrict__ usq, float* __restrict__ vsq)
{
    int row = blockIdx.x;
    const float* src;
    unsigned short* dst;
    float* sq;
    if (row < N_DIM) {
        src = U + (size_t)row * D_DIM;
        dst = Ub + (size_t)row * D_DIM;
        sq  = usq + row;
    } else {
        int r = row - N_DIM;
        src = V + (size_t)r * D_DIM;
        dst = Vb + (size_t)r * D_DIM;
        sq  = vsq + r;
    }
    int t = threadIdx.x;
    float2 v = *reinterpret_cast<const float2*>(src + 2 * t);
    float s = v.x * v.x + v.y * v.y;
    ushort2 b;
    b.x = f2bf(v.x);
    b.y = f2bf(v.y);
    *reinterpret_cast<ushort2*>(dst + 2 * t) = b;

    #pragma unroll
    for (int o = 32; o > 0; o >>= 1) s += __shfl_down(s, o, 64);
    __shared__ float red[4];
    if ((t & 63) == 0) red[t >> 6] = s;
    __syncthreads();
    if (t == 0) *sq = red[0] + red[1] + red[2] + red[3];
}

// ---------------- fused GEMM + loss, 4-tile pipelined per block ----------------
// Per tile: K-loop (global_load_lds staging, XOR-swizzled ds_read, mfma) with
// the PREVIOUS tile's M/W streaming interleaved (prefetch-1 register dbuf,
// consumed after the MFMAs, rec read back from a bf16 LDS buffer).
// After each K-loop the full 128x128 acc is dumped to LDS as bf16, so only
// ONE accumulator set is ever live (no spills). Last tile's epilogue exposed.
__global__ void __launch_bounds__(256, 2) fused_kernel(
    const unsigned short* __restrict__ Ub, const unsigned short* __restrict__ Vb,
    const float* __restrict__ Mg, const float* __restrict__ Wg,
    const float* __restrict__ usq, const float* __restrict__ vsq,
    double* __restrict__ acc)
{
    __shared__ alignas(16) char smem[BM * BK * 2 + BN * BK * 2];   // 32 KiB staging
    __shared__ alignas(16) unsigned short recs[BM * RSTR];         // 34 KiB bf16 rec
    __shared__ float red1[4], red2[4];
    char* As = smem;
    char* Bs = smem + BM * BK * 2;

    const int t    = threadIdx.x;
    const int lane = t & 63;
    const int wave = t >> 6;
    const int wm   = wave >> 1;
    const int wn   = wave & 1;

    const int bid    = blockIdx.x;   // 0..1023
    const int tile_m = bid >> 4;
    const int quad   = bid & 15;
    const int row0   = tile_m * BM;

    const int rg = t >> 4;     // 0..15 (row within 16-row chunk)
    const int ct = t & 15;     // 0..15
    const int c8 = ct * 8;     // 0..120 (8-float column slice)

    float s1 = 0.f, s2 = 0.f;

    auto As3 = (__attribute__((address_space(3))) char*)As;
    auto Bs3 = (__attribute__((address_space(3))) char*)Bs;

    auto stage = [&](const unsigned short* Ua, const unsigned short* Va, int k0) {
        #pragma unroll
        for (int c = 0; c < 4; ++c) {
            int s   = c * 256 + t;
            int row = s >> 3;
            int kg  = s & 7;
            int kgs = kg ^ (row & 7);    // inverse-swizzled global source
            __builtin_amdgcn_global_load_lds(
                (const __attribute__((address_space(1))) void*)(Ua + (size_t)row * D_DIM + k0 + kgs * 8),
                (__attribute__((address_space(3))) void*)(As3 + s * 16), 16, 0, 0);
            __builtin_amdgcn_global_load_lds(
                (const __attribute__((address_space(1))) void*)(Va + (size_t)row * D_DIM + k0 + kgs * 8),
                (__attribute__((address_space(3))) void*)(Bs3 + s * 16), 16, 0, 0);
        }
    };

    auto mma = [&](f32x4 (&a)[4][4]) {
        #pragma unroll
        for (int kc = 0; kc < 2; ++kc) {
            bf16x8 af[4], bfr[4];
            const int kgw = kc * 4 + (lane >> 4);
            #pragma unroll
            for (int i = 0; i < 4; ++i) {
                int ra = wm * 64 + i * 16 + (lane & 15);
                af[i]  = *reinterpret_cast<const bf16x8*>(As + ra * (BK * 2) + ((kgw ^ (ra & 7)) * 16));
                int rb = wn * 64 + i * 16 + (lane & 15);
                bfr[i] = *reinterpret_cast<const bf16x8*>(Bs + rb * (BK * 2) + ((kgw ^ (rb & 7)) * 16));
            }
            #pragma unroll
            for (int i = 0; i < 4; ++i)
                #pragma unroll
                for (int j = 0; j < 4; ++j)
                    a[i][j] = __builtin_amdgcn_mfma_f32_16x16x32_bf16(af[i], bfr[j], a[i][j], 0, 0, 0);
        }
    };

    // C/D layout (16x16x32): col = lane&15, row = (lane>>4)*4 + reg
    auto dump = [&](f32x4 (&a)[4][4]) {
        #pragma unroll
        for (int i = 0; i < 4; ++i)
            #pragma unroll
            for (int j = 0; j < 4; ++j)
                #pragma unroll
                for (int q = 0; q < 4; ++q) {
                    int r = wm * 64 + i * 16 + (lane >> 4) * 4 + q;
                    int c = wn * 64 + j * 16 + (lane & 15);
                    recs[r * RSTR + c] = f2bf(a[i][j][q]);
                }
    };

    int   colp = 0;            // column base of the tile being streamed
    f32x4 vs0v, vs1v;

    auto issue = [&](int chunk, f32x4& m0, f32x4& m1, f32x4& w0, f32x4& w1, float& us) {
        int r = chunk * 16 + rg;
        const float* Mp = Mg + (size_t)(row0 + r) * N_DIM + colp + c8;
        const float* Wp = Wg + (size_t)(row0 + r) * N_DIM + colp + c8;
        m0 = *reinterpret_cast<const f32x4*>(Mp);
        m1 = *reinterpret_cast<const f32x4*>(Mp + 4);
        w0 = *reinterpret_cast<const f32x4*>(Wp);
        w1 = *reinterpret_cast<const f32x4*>(Wp + 4);
        us = usq[row0 + r];
    };

    auto consume = [&](int chunk, f32x4 m0, f32x4 m1, f32x4 w0, f32x4 w1, float us) {
        int r = chunk * 16 + rg;
        bf16x8 rb = *reinterpret_cast<const bf16x8*>(&recs[r * RSTR + c8]);
        #pragma unroll
        for (int c = 0; c < 4; ++c) {
            float rc = bf2f((unsigned short)rb[c]);
            float d  = rc - m0[c];
            s1 = fmaf(d, d, s1);
            s2 = fmaf(w0[c], us + vs0v[c] - 2.f * rc, s2);
        }
        #pragma unroll
        for (int c = 0; c < 4; ++c) {
            float rc = bf2f((unsigned short)rb[4 + c]);
            float d  = rc - m1[c];
            s1 = fmaf(d, d, s1);
            s2 = fmaf(w1[c], us + vs1v[c] - 2.f * rc, s2);
        }
    };

    const f32x4 zero = {0.f, 0.f, 0.f, 0.f};
    const unsigned short* Ua = Ub + (size_t)row0 * D_DIM;

    f32x4 a[4][4];
    f32x4 mvA[2], wvA[2], mvB[2], wvB[2];
    float usA, usB;

    for (int it = 0; it < TPB; ++it) {
        const int col0 = (quad * TPB + it) * BN;
        const unsigned short* Va = Vb + (size_t)col0 * D_DIM;
        const bool strm = (it > 0);

        #pragma unroll
        for (int i = 0; i < 4; ++i)
            #pragma unroll
            for (int j = 0; j < 4; ++j) a[i][j] = zero;

        if (strm) {
            colp = (quad * TPB + it - 1) * BN;
            vs0v = *reinterpret_cast<const f32x4*>(vsq + colp + c8);
            vs1v = *reinterpret_cast<const f32x4*>(vsq + colp + c8 + 4);
            issue(0, mvA[0], mvA[1], wvA[0], wvA[1], usA);
        }

        #pragma unroll
        for (int kt = 0; kt < D_DIM / BK; ++kt) {
            stage(Ua, Va, kt * BK);
            __syncthreads();            // also orders previous tile's dump vs consume
            if (strm && kt < 7) {
                if (kt & 1) issue(kt + 1, mvA[0], mvA[1], wvA[0], wvA[1], usA);
                else        issue(kt + 1, mvB[0], mvB[1], wvB[0], wvB[1], usB);
            }
            mma(a);
            if (strm) {
                if (kt & 1) consume(kt, mvB[0], mvB[1], wvB[0], wvB[1], usB);
                else        consume(kt, mvA[0], mvA[1], wvA[0], wvA[1], usA);
            }
            __syncthreads();
        }
        dump(a);                         // safe: all recs reads done before last barrier
    }

    // ---- exposed epilogue for the last tile ----
    colp = (quad * TPB + TPB - 1) * BN;
    vs0v = *reinterpret_cast<const f32x4*>(vsq + colp + c8);
    vs1v = *reinterpret_cast<const f32x4*>(vsq + colp + c8 + 4);
    __syncthreads();                     // dump visible to all waves
    issue(0, mvA[0], mvA[1], wvA[0], wvA[1], usA);
    #pragma unroll
    for (int chunk = 0; chunk < 8; ++chunk) {
        if (chunk < 7) {
            if (chunk & 1) issue(chunk + 1, mvA[0], mvA[1], wvA[0], wvA[1], usA);
            else           issue(chunk + 1, mvB[0], mvB[1], wvB[0], wvB[1], usB);
        }
        if (chunk & 1) consume(chunk, mvB[0], mvB[1], wvB[0], wvB[1], usB);
        else           consume(chunk, mvA[0], mvA[1], wvA[0], wvA[1], usA);
    }

    // ---- block reduction + atomics ----
    #pragma unroll
    for (int o = 32; o > 0; o >>= 1) {
        s1 += __shfl_down(s1, o, 64);
        s2 += __shfl_down(s2, o, 64);
    }
    if (lane == 0) { red1[wave] = s1; red2[wave] = s2; }
    __syncthreads();
    if (t == 0) {
        double a1s = (double)red1[0] + red1[1] + red1[2] + red1[3];
        double a2s = (double)red2[0] + red2[1] + red2[2] + red2[3];
        atomicAdd(acc, a1s);
        atomicAdd(acc + 1, a2s);
    }
}

// ---------------- finalize ----------------
__global__ void finalize_kernel(const double* __restrict__ acc,
                                const float* __restrict__ alpha,
                                float* __restrict__ out)
{
    double tot = acc[0] + (double)alpha[0] * acc[1];
    out[0] = (float)(tot / ((double)N_DIM * (double)N_DIM));
}

extern "C" void kernel_launch(void* const* d_in, const int* in_sizes, int n_in,
                              void* d_out, int out_size, void* d_ws, size_t ws_size,
                              hipStream_t stream) {
    const float* U     = (const float*)d_in[0];
    const float* V     = (const float*)d_in[1];
    const float* Mg    = (const float*)d_in[2];
    const float* Wg    = (const float*)d_in[3];
    const float* alpha = (const float*)d_in[4];

    char* ws = (char*)d_ws;
    unsigned short* Ub = (unsigned short*)ws;                          // 8 MiB
    unsigned short* Vb = (unsigned short*)(ws + 8u * 1024 * 1024);     // 8 MiB
    float* usq = (float*)(ws + 16u * 1024 * 1024);                     // 32 KiB
    float* vsq = (float*)(ws + 16u * 1024 * 1024 + 32u * 1024);       // 32 KiB
    double* acc = (double*)(ws + 16u * 1024 * 1024 + 64u * 1024);     // 16 B

    hipMemsetAsync(acc, 0, 2 * sizeof(double), stream);
    prep_kernel<<<2 * N_DIM, 256, 0, stream>>>(U, V, Ub, Vb, usq, vsq);
    fused_kernel<<<(N_DIM / BM) * (N_DIM / BN) / TPB, 256, 0, stream>>>(
        Ub, Vb, Mg, Wg, usq, vsq, acc);
    finalize_kernel<<<1, 1, 0, stream>>>(acc, alpha, (float*)d_out);
}

// Round 5
// 181.812 us; speedup vs baseline: 1.5066x; 1.2027x over previous
//
#include <hip/hip_runtime.h>
#include <hip/hip_bf16.h>
#include <stdint.h>

#define N_DIM 8192
#define D_DIM 512
#define BM 128
#define BN 128
#define BK 64
#define RSTR 140   // recs row stride in bf16 elems: 280 B/row -> 24-bank rotation/row

typedef __attribute__((ext_vector_type(8))) short bf16x8;
typedef __attribute__((ext_vector_type(4))) float f32x4;

__device__ __forceinline__ unsigned short f2bf(float f) {
    unsigned int x = __float_as_uint(f);
    x += 0x7fffu + ((x >> 16) & 1u);
    return (unsigned short)(x >> 16);
}
__device__ __forceinline__ float bf2f(unsigned short u) {
    return __uint_as_float(((unsigned int)u) << 16);
}

// ---------------- prep: f32 -> bf16, plus row squared norms ----------------
__global__ void __launch_bounds__(256) prep_kernel(
    const float* __restrict__ U, const float* __restrict__ V,
    unsigned short* __restrict__ Ub, unsigned short* __restrict__ Vb,
    float* __restrict__ usq, float* __restrict__ vsq)
{
    int row = blockIdx.x;
    const float* src;
    unsigned short* dst;
    float* sq;
    if (row < N_DIM) {
        src = U + (size_t)row * D_DIM;
        dst = Ub + (size_t)row * D_DIM;
        sq  = usq + row;
    } else {
        int r = row - N_DIM;
        src = V + (size_t)r * D_DIM;
        dst = Vb + (size_t)r * D_DIM;
        sq  = vsq + r;
    }
    int t = threadIdx.x;
    float2 v = *reinterpret_cast<const float2*>(src + 2 * t);
    float s = v.x * v.x + v.y * v.y;
    ushort2 b;
    b.x = f2bf(v.x);
    b.y = f2bf(v.y);
    *reinterpret_cast<ushort2*>(dst + 2 * t) = b;

    #pragma unroll
    for (int o = 32; o > 0; o >>= 1) s += __shfl_down(s, o, 64);
    __shared__ float red[4];
    if ((t & 63) == 0) red[t >> 6] = s;
    __syncthreads();
    if (t == 0) *sq = red[0] + red[1] + red[2] + red[3];
}

// ---------------- fused GEMM + loss-reduction kernel ----------------
// Two clean phases per block (round-1 structure):
//   1) 128x128 GEMM: global_load_lds staging (linear LDS dest, inverse-swizzled
//      global source), XOR-swizzled ds_read_b128, mfma 16x16x32.
//   2) Full acc -> LDS as bf16 (acc regs die), then a depth-3 software-pipelined
//      M/W stream: 8 chunks x (2xf32x4 M + 2xf32x4 W), 192 B/lane in flight.
// Cross-phase overlap comes from 16 sequential block-slots per CU.
__global__ void __launch_bounds__(256, 2) fused_kernel(
    const unsigned short* __restrict__ Ub, const unsigned short* __restrict__ Vb,
    const float* __restrict__ Mg, const float* __restrict__ Wg,
    const float* __restrict__ usq, const float* __restrict__ vsq,
    double* __restrict__ acc)
{
    __shared__ alignas(16) char smem[BM * BK * 2 + BN * BK * 2];   // 32 KiB staging
    __shared__ alignas(16) unsigned short recs[BM * RSTR];          // 35 KiB bf16 rec
    __shared__ float red1[4], red2[4];
    char* As = smem;
    char* Bs = smem + BM * BK * 2;

    const int t    = threadIdx.x;
    const int lane = t & 63;
    const int wave = t >> 6;
    const int wm   = wave >> 1;
    const int wn   = wave & 1;

    const int bid    = blockIdx.x;          // row-major over tiles (round-1 map)
    const int tile_m = bid >> 6;
    const int tile_n = bid & 63;
    const int row0   = tile_m * BM;
    const int col0   = tile_n * BN;

    const f32x4 zero = {0.f, 0.f, 0.f, 0.f};
    f32x4 a[4][4];
    #pragma unroll
    for (int i = 0; i < 4; ++i)
        #pragma unroll
        for (int j = 0; j < 4; ++j) a[i][j] = zero;

    auto As3 = (__attribute__((address_space(3))) char*)As;
    auto Bs3 = (__attribute__((address_space(3))) char*)Bs;

    for (int kt = 0; kt < D_DIM / BK; ++kt) {
        const int k0 = kt * BK;
        #pragma unroll
        for (int c = 0; c < 4; ++c) {
            int s   = c * 256 + t;
            int row = s >> 3;
            int kg  = s & 7;
            int kgs = kg ^ (row & 7);    // inverse-swizzled global source
            __builtin_amdgcn_global_load_lds(
                (const __attribute__((address_space(1))) void*)(Ub + (size_t)(row0 + row) * D_DIM + k0 + kgs * 8),
                (__attribute__((address_space(3))) void*)(As3 + s * 16), 16, 0, 0);
            __builtin_amdgcn_global_load_lds(
                (const __attribute__((address_space(1))) void*)(Vb + (size_t)(col0 + row) * D_DIM + k0 + kgs * 8),
                (__attribute__((address_space(3))) void*)(Bs3 + s * 16), 16, 0, 0);
        }
        __syncthreads();

        #pragma unroll
        for (int kc = 0; kc < 2; ++kc) {
            bf16x8 af[4], bfr[4];
            const int kgw = kc * 4 + (lane >> 4);
            #pragma unroll
            for (int i = 0; i < 4; ++i) {
                int ra = wm * 64 + i * 16 + (lane & 15);
                af[i]  = *reinterpret_cast<const bf16x8*>(As + ra * (BK * 2) + ((kgw ^ (ra & 7)) * 16));
                int rb = wn * 64 + i * 16 + (lane & 15);
                bfr[i] = *reinterpret_cast<const bf16x8*>(Bs + rb * (BK * 2) + ((kgw ^ (rb & 7)) * 16));
            }
            #pragma unroll
            for (int i = 0; i < 4; ++i)
                #pragma unroll
                for (int j = 0; j < 4; ++j)
                    a[i][j] = __builtin_amdgcn_mfma_f32_16x16x32_bf16(af[i], bfr[j], a[i][j], 0, 0, 0);
        }
        __syncthreads();
    }

    // ---- epilogue ----
    const int rg = t >> 4;          // 0..15: row within 16-row chunk
    const int c8 = (t & 15) * 8;    // 0..120: 8-float column slice

    const f32x4 vs0 = *reinterpret_cast<const f32x4*>(vsq + col0 + c8);
    const f32x4 vs1 = *reinterpret_cast<const f32x4*>(vsq + col0 + c8 + 4);

    float s1 = 0.f, s2 = 0.f;

    f32x4 m0[3], m1[3], w0[3], w1[3];
    float us[3];

    auto issue = [&](int chunk, int slot) {
        int r = chunk * 16 + rg;
        const float* Mp = Mg + (size_t)(row0 + r) * N_DIM + col0 + c8;
        const float* Wp = Wg + (size_t)(row0 + r) * N_DIM + col0 + c8;
        m0[slot] = *reinterpret_cast<const f32x4*>(Mp);
        m1[slot] = *reinterpret_cast<const f32x4*>(Mp + 4);
        w0[slot] = *reinterpret_cast<const f32x4*>(Wp);
        w1[slot] = *reinterpret_cast<const f32x4*>(Wp + 4);
        us[slot] = usq[row0 + r];
    };

    // hoist first 3 chunk-loads above the dump barrier (independent of recs)
    issue(0, 0);
    issue(1, 1);
    issue(2, 2);

    // dump full acc tile to LDS as bf16 -> acc registers die here
    // C/D layout (16x16x32): col = lane&15, row = (lane>>4)*4 + reg
    #pragma unroll
    for (int i = 0; i < 4; ++i)
        #pragma unroll
        for (int j = 0; j < 4; ++j)
            #pragma unroll
            for (int q = 0; q < 4; ++q) {
                int r = wm * 64 + i * 16 + (lane >> 4) * 4 + q;
                int c = wn * 64 + j * 16 + (lane & 15);
                recs[r * RSTR + c] = f2bf(a[i][j][q]);
            }
    __syncthreads();

    #pragma unroll
    for (int chunk = 0; chunk < 8; ++chunk) {
        const int slot = chunk % 3;
        int r = chunk * 16 + rg;
        bf16x8 rb = *reinterpret_cast<const bf16x8*>(&recs[r * RSTR + c8]);
        f32x4 lm0 = m0[slot], lm1 = m1[slot], lw0 = w0[slot], lw1 = w1[slot];
        float lus = us[slot];
        if (chunk + 3 < 8) issue(chunk + 3, slot);
        #pragma unroll
        for (int c = 0; c < 4; ++c) {
            float rc = bf2f((unsigned short)rb[c]);
            float d  = rc - lm0[c];
            s1 = fmaf(d, d, s1);
            s2 = fmaf(lw0[c], lus + vs0[c] - 2.f * rc, s2);
        }
        #pragma unroll
        for (int c = 0; c < 4; ++c) {
            float rc = bf2f((unsigned short)rb[4 + c]);
            float d  = rc - lm1[c];
            s1 = fmaf(d, d, s1);
            s2 = fmaf(lw1[c], lus + vs1[c] - 2.f * rc, s2);
        }
    }

    // ---- block reduction + atomics ----
    #pragma unroll
    for (int o = 32; o > 0; o >>= 1) {
        s1 += __shfl_down(s1, o, 64);
        s2 += __shfl_down(s2, o, 64);
    }
    if (lane == 0) { red1[wave] = s1; red2[wave] = s2; }
    __syncthreads();
    if (t == 0) {
        double a1s = (double)red1[0] + red1[1] + red1[2] + red1[3];
        double a2s = (double)red2[0] + red2[1] + red2[2] + red2[3];
        atomicAdd(acc, a1s);
        atomicAdd(acc + 1, a2s);
    }
}

// ---------------- finalize ----------------
__global__ void finalize_kernel(const double* __restrict__ acc,
                                const float* __restrict__ alpha,
                                float* __restrict__ out)
{
    double tot = acc[0] + (double)alpha[0] * acc[1];
    out[0] = (float)(tot / ((double)N_DIM * (double)N_DIM));
}

extern "C" void kernel_launch(void* const* d_in, const int* in_sizes, int n_in,
                              void* d_out, int out_size, void* d_ws, size_t ws_size,
                              hipStream_t stream) {
    const float* U     = (const float*)d_in[0];
    const float* V     = (const float*)d_in[1];
    const float* Mg    = (const float*)d_in[2];
    const float* Wg    = (const float*)d_in[3];
    const float* alpha = (const float*)d_in[4];

    char* ws = (char*)d_ws;
    unsigned short* Ub = (unsigned short*)ws;                          // 8 MiB
    unsigned short* Vb = (unsigned short*)(ws + 8u * 1024 * 1024);     // 8 MiB
    float* usq = (float*)(ws + 16u * 1024 * 1024);                     // 32 KiB
    float* vsq = (float*)(ws + 16u * 1024 * 1024 + 32u * 1024);       // 32 KiB
    double* acc = (double*)(ws + 16u * 1024 * 1024 + 64u * 1024);     // 16 B

    hipMemsetAsync(acc, 0, 2 * sizeof(double), stream);
    prep_kernel<<<2 * N_DIM, 256, 0, stream>>>(U, V, Ub, Vb, usq, vsq);
    fused_kernel<<<(N_DIM / BM) * (N_DIM / BN), 256, 0, stream>>>(
        Ub, Vb, Mg, Wg, usq, vsq, acc);
    finalize_kernel<<<1, 1, 0, stream>>>(acc, alpha, (float*)d_out);
}

// Round 6
// 178.746 us; speedup vs baseline: 1.5324x; 1.0172x over previous
//
#include <hip/hip_runtime.h>
#include <hip/hip_bf16.h>
#include <stdint.h>

#define N_DIM 8192
#define D_DIM 512
#define BM 128
#define BN 128
#define BK 64
#define RSTR 140   // recs row stride in bf16 elems
#define TPB 4      // tiles chained per block (same tile_m row)

typedef __attribute__((ext_vector_type(8))) short bf16x8;
typedef __attribute__((ext_vector_type(4))) float f32x4;
typedef __attribute__((ext_vector_type(4))) unsigned int u32x4;

__device__ __forceinline__ unsigned short f2bf(float f) {
    unsigned int x = __float_as_uint(f);
    x += 0x7fffu + ((x >> 16) & 1u);
    return (unsigned short)(x >> 16);
}
__device__ __forceinline__ float bf2f(unsigned short u) {
    return __uint_as_float(((unsigned int)u) << 16);
}

// ---------------- prep: f32 -> bf16, plus row squared norms ----------------
__global__ void __launch_bounds__(256) prep_kernel(
    const float* __restrict__ U, const float* __restrict__ V,
    unsigned short* __restrict__ Ub, unsigned short* __restrict__ Vb,
    float* __restrict__ usq, float* __restrict__ vsq)
{
    int row = blockIdx.x;
    const float* src;
    unsigned short* dst;
    float* sq;
    if (row < N_DIM) {
        src = U + (size_t)row * D_DIM;
        dst = Ub + (size_t)row * D_DIM;
        sq  = usq + row;
    } else {
        int r = row - N_DIM;
        src = V + (size_t)r * D_DIM;
        dst = Vb + (size_t)r * D_DIM;
        sq  = vsq + r;
    }
    int t = threadIdx.x;
    float2 v = *reinterpret_cast<const float2*>(src + 2 * t);
    float s = v.x * v.x + v.y * v.y;
    ushort2 b;
    b.x = f2bf(v.x);
    b.y = f2bf(v.y);
    *reinterpret_cast<ushort2*>(dst + 2 * t) = b;

    #pragma unroll
    for (int o = 32; o > 0; o >>= 1) s += __shfl_down(s, o, 64);
    __shared__ float red[4];
    if ((t & 63) == 0) red[t >> 6] = s;
    __syncthreads();
    if (t == 0) *sq = red[0] + red[1] + red[2] + red[3];
}

// ---------------- fused GEMM + loss, tile-chained, non-draining barriers ----------------
// Reg-staging (global->reg->ds_write) moves the staging hazard to lgkmcnt;
// barriers are raw s_barrier + s_waitcnt lgkmcnt(0) ONLY — M/W stream loads
// (vmcnt) are never drained and fly for a full K-step under the MFMAs.
// Tile i-1's M/W (1 chunk of 16 rows / K-step) streams inside tile i's K-loop,
// rec read back from the bf16 LDS handoff buffer; last tile exposed.
__global__ void __launch_bounds__(256, 2) fused_kernel(
    const unsigned short* __restrict__ Ub, const unsigned short* __restrict__ Vb,
    const float* __restrict__ Mg, const float* __restrict__ Wg,
    const float* __restrict__ usq, const float* __restrict__ vsq,
    double* __restrict__ acc)
{
    __shared__ alignas(16) char smem[BM * BK * 2 + BN * BK * 2];   // 32 KiB staging
    __shared__ alignas(16) unsigned short recs[BM * RSTR];          // 35 KiB bf16 rec
    __shared__ float red1[4], red2[4];
    char* As = smem;
    char* Bs = smem + BM * BK * 2;

    const int t    = threadIdx.x;
    const int lane = t & 63;
    const int wave = t >> 6;
    const int wm   = wave >> 1;
    const int wn   = wave & 1;

    const int bid    = blockIdx.x;   // 0..1023
    const int tile_m = bid >> 4;
    const int quad   = bid & 15;
    const int row0   = tile_m * BM;

    const int rg = t >> 4;           // 0..15: row within 16-row chunk
    const int c8 = (t & 15) * 8;     // 0..120: 8-float column slice

    float s1 = 0.f, s2 = 0.f;

    // ---- streaming state (two named register sets; rule #20) ----
    int   colp = 0;
    f32x4 vs0, vs1;
    f32x4 mA0, mA1, wA0, wA1; float usA;
    f32x4 mB0, mB1, wB0, wB1; float usB;

    auto issueA = [&](int chunk) {
        int r = chunk * 16 + rg;
        const float* Mp = Mg + (size_t)(row0 + r) * N_DIM + colp + c8;
        const float* Wp = Wg + (size_t)(row0 + r) * N_DIM + colp + c8;
        mA0 = *reinterpret_cast<const f32x4*>(Mp);
        mA1 = *reinterpret_cast<const f32x4*>(Mp + 4);
        wA0 = *reinterpret_cast<const f32x4*>(Wp);
        wA1 = *reinterpret_cast<const f32x4*>(Wp + 4);
        usA = usq[row0 + r];
    };
    auto issueB = [&](int chunk) {
        int r = chunk * 16 + rg;
        const float* Mp = Mg + (size_t)(row0 + r) * N_DIM + colp + c8;
        const float* Wp = Wg + (size_t)(row0 + r) * N_DIM + colp + c8;
        mB0 = *reinterpret_cast<const f32x4*>(Mp);
        mB1 = *reinterpret_cast<const f32x4*>(Mp + 4);
        wB0 = *reinterpret_cast<const f32x4*>(Wp);
        wB1 = *reinterpret_cast<const f32x4*>(Wp + 4);
        usB = usq[row0 + r];
    };
    auto consumeA = [&](int chunk) {
        int r = chunk * 16 + rg;
        bf16x8 rb = *reinterpret_cast<const bf16x8*>(&recs[r * RSTR + c8]);
        #pragma unroll
        for (int c = 0; c < 4; ++c) {
            float rc = bf2f((unsigned short)rb[c]);
            float d  = rc - mA0[c];
            s1 = fmaf(d, d, s1);
            s2 = fmaf(wA0[c], usA + vs0[c] - 2.f * rc, s2);
        }
        #pragma unroll
        for (int c = 0; c < 4; ++c) {
            float rc = bf2f((unsigned short)rb[4 + c]);
            float d  = rc - mA1[c];
            s1 = fmaf(d, d, s1);
            s2 = fmaf(wA1[c], usA + vs1[c] - 2.f * rc, s2);
        }
    };
    auto consumeB = [&](int chunk) {
        int r = chunk * 16 + rg;
        bf16x8 rb = *reinterpret_cast<const bf16x8*>(&recs[r * RSTR + c8]);
        #pragma unroll
        for (int c = 0; c < 4; ++c) {
            float rc = bf2f((unsigned short)rb[c]);
            float d  = rc - mB0[c];
            s1 = fmaf(d, d, s1);
            s2 = fmaf(wB0[c], usB + vs0[c] - 2.f * rc, s2);
        }
        #pragma unroll
        for (int c = 0; c < 4; ++c) {
            float rc = bf2f((unsigned short)rb[4 + c]);
            float d  = rc - mB1[c];
            s1 = fmaf(d, d, s1);
            s2 = fmaf(wB1[c], usB + vs1[c] - 2.f * rc, s2);
        }
    };

    // ---- staging: global->reg (vmcnt), then ds_write swizzled (lgkm) ----
    auto stage_load = [&](const unsigned short* Ua, const unsigned short* Va, int k0,
                          u32x4 (&sa)[4], u32x4 (&sb)[4]) {
        #pragma unroll
        for (int c = 0; c < 4; ++c) {
            int s   = c * 256 + t;
            int row = s >> 3;
            int kg  = s & 7;
            sa[c] = *reinterpret_cast<const u32x4*>(Ua + (size_t)row * D_DIM + k0 + kg * 8);
            sb[c] = *reinterpret_cast<const u32x4*>(Va + (size_t)row * D_DIM + k0 + kg * 8);
        }
    };
    auto stage_write = [&](u32x4 (&sa)[4], u32x4 (&sb)[4]) {
        #pragma unroll
        for (int c = 0; c < 4; ++c) {
            int s   = c * 256 + t;
            int row = s >> 3;
            int kg  = s & 7;
            int kgs = kg ^ (row & 7);
            *reinterpret_cast<u32x4*>(As + row * (BK * 2) + kgs * 16) = sa[c];
            *reinterpret_cast<u32x4*>(Bs + row * (BK * 2) + kgs * 16) = sb[c];
        }
    };

    auto mma = [&](f32x4 (&a)[4][4]) {
        #pragma unroll
        for (int kc = 0; kc < 2; ++kc) {
            bf16x8 af[4], bfr[4];
            const int kgw = kc * 4 + (lane >> 4);
            #pragma unroll
            for (int i = 0; i < 4; ++i) {
                int ra = wm * 64 + i * 16 + (lane & 15);
                af[i]  = *reinterpret_cast<const bf16x8*>(As + ra * (BK * 2) + ((kgw ^ (ra & 7)) * 16));
                int rb = wn * 64 + i * 16 + (lane & 15);
                bfr[i] = *reinterpret_cast<const bf16x8*>(Bs + rb * (BK * 2) + ((kgw ^ (rb & 7)) * 16));
            }
            #pragma unroll
            for (int i = 0; i < 4; ++i)
                #pragma unroll
                for (int j = 0; j < 4; ++j)
                    a[i][j] = __builtin_amdgcn_mfma_f32_16x16x32_bf16(af[i], bfr[j], a[i][j], 0, 0, 0);
        }
    };

    // C/D layout (16x16x32): col = lane&15, row = (lane>>4)*4 + reg
    auto dump = [&](f32x4 (&a)[4][4]) {
        #pragma unroll
        for (int i = 0; i < 4; ++i)
            #pragma unroll
            for (int j = 0; j < 4; ++j)
                #pragma unroll
                for (int q = 0; q < 4; ++q) {
                    int r = wm * 64 + i * 16 + (lane >> 4) * 4 + q;
                    int c = wn * 64 + j * 16 + (lane & 15);
                    recs[r * RSTR + c] = f2bf(a[i][j][q]);
                }
    };

    const f32x4 zero = {0.f, 0.f, 0.f, 0.f};
    const unsigned short* Ua = Ub + (size_t)row0 * D_DIM;
    f32x4 a[4][4];
    u32x4 sa[4], sb[4];

    #define FENCE() asm volatile("" ::: "memory")
    #define LGKM0_BAR() do { \
        asm volatile("s_waitcnt lgkmcnt(0)" ::: "memory"); \
        __builtin_amdgcn_s_barrier(); } while (0)

    for (int it = 0; it < TPB; ++it) {
        const int col0 = (quad * TPB + it) * BN;
        const unsigned short* Va = Vb + (size_t)col0 * D_DIM;
        const bool strm = (it > 0);

        #pragma unroll
        for (int i = 0; i < 4; ++i)
            #pragma unroll
            for (int j = 0; j < 4; ++j) a[i][j] = zero;

        if (strm) {
            colp = col0 - BN;
            vs0 = *reinterpret_cast<const f32x4*>(vsq + colp + c8);
            vs1 = *reinterpret_cast<const f32x4*>(vsq + colp + c8 + 4);
            issueA(0);
        }

        for (int kt2 = 0; kt2 < 4; ++kt2) {
            const int kt = kt2 * 2;
            // ---- even K-step: consume set A (chunk kt), prefetch set B (kt+1) ----
            stage_load(Ua, Va, kt * BK, sa, sb);
            FENCE();                              // M/W loads stay YOUNGER than stage loads
            if (strm) issueB(kt + 1);
            FENCE();
            stage_write(sa, sb);                  // compiler waits counted vmcnt (leaves M/W flying)
            LGKM0_BAR();
            mma(a);
            if (strm) consumeA(kt);               // compiler vmcnt-waits set A here (late)
            LGKM0_BAR();

            // ---- odd K-step: consume set B (chunk kt+1), prefetch set A (kt+2) ----
            stage_load(Ua, Va, (kt + 1) * BK, sa, sb);
            FENCE();
            if (strm && kt2 < 3) issueA(kt + 2);
            FENCE();
            stage_write(sa, sb);
            LGKM0_BAR();
            mma(a);
            if (strm) consumeB(kt + 1);
            LGKM0_BAR();
        }
        dump(a);   // next consume is after the following lgkm0+barrier -> visible
    }

    // ---- exposed epilogue for the last tile (depth-2 pipelined) ----
    colp = (quad * TPB + TPB - 1) * BN;
    vs0 = *reinterpret_cast<const f32x4*>(vsq + colp + c8);
    vs1 = *reinterpret_cast<const f32x4*>(vsq + colp + c8 + 4);
    LGKM0_BAR();                                  // dump visible to all waves
    issueA(0);
    issueB(1);
    consumeA(0); issueA(2);
    consumeB(1); issueB(3);
    consumeA(2); issueA(4);
    consumeB(3); issueB(5);
    consumeA(4); issueA(6);
    consumeB(5); issueB(7);
    consumeA(6);
    consumeB(7);

    // ---- block reduction + atomics ----
    #pragma unroll
    for (int o = 32; o > 0; o >>= 1) {
        s1 += __shfl_down(s1, o, 64);
        s2 += __shfl_down(s2, o, 64);
    }
    if (lane == 0) { red1[wave] = s1; red2[wave] = s2; }
    __syncthreads();
    if (t == 0) {
        double a1s = (double)red1[0] + red1[1] + red1[2] + red1[3];
        double a2s = (double)red2[0] + red2[1] + red2[2] + red2[3];
        atomicAdd(acc, a1s);
        atomicAdd(acc + 1, a2s);
    }
    #undef FENCE
    #undef LGKM0_BAR
}

// ---------------- finalize ----------------
__global__ void finalize_kernel(const double* __restrict__ acc,
                                const float* __restrict__ alpha,
                                float* __restrict__ out)
{
    double tot = acc[0] + (double)alpha[0] * acc[1];
    out[0] = (float)(tot / ((double)N_DIM * (double)N_DIM));
}

extern "C" void kernel_launch(void* const* d_in, const int* in_sizes, int n_in,
                              void* d_out, int out_size, void* d_ws, size_t ws_size,
                              hipStream_t stream) {
    const float* U     = (const float*)d_in[0];
    const float* V     = (const float*)d_in[1];
    const float* Mg    = (const float*)d_in[2];
    const float* Wg    = (const float*)d_in[3];
    const float* alpha = (const float*)d_in[4];

    char* ws = (char*)d_ws;
    unsigned short* Ub = (unsigned short*)ws;                          // 8 MiB
    unsigned short* Vb = (unsigned short*)(ws + 8u * 1024 * 1024);     // 8 MiB
    float* usq = (float*)(ws + 16u * 1024 * 1024);                     // 32 KiB
    float* vsq = (float*)(ws + 16u * 1024 * 1024 + 32u * 1024);       // 32 KiB
    double* acc = (double*)(ws + 16u * 1024 * 1024 + 64u * 1024);     // 16 B

    hipMemsetAsync(acc, 0, 2 * sizeof(double), stream);
    prep_kernel<<<2 * N_DIM, 256, 0, stream>>>(U, V, Ub, Vb, usq, vsq);
    fused_kernel<<<(N_DIM / BM) * (N_DIM / BN) / TPB, 256, 0, stream>>>(
        Ub, Vb, Mg, Wg, usq, vsq, acc);
    finalize_kernel<<<1, 1, 0, stream>>>(acc, alpha, (float*)d_out);
}